// Round 1
// baseline (152.837 us; speedup 1.0000x reference)
//
#include <hip/hip_runtime.h>
#include <math.h>

#define BB 8
#define NN 256
#define DD 128

// ---------------- Kernel A: h = node@Wn+bn, ti = node@We1[:D]+be1, aj = node@We1[D:2D]
#define RT 8
__global__ __launch_bounds__(128) void prep_kernel(
    const float* __restrict__ node, const float* __restrict__ Wn,
    const float* __restrict__ bn, const float* __restrict__ We1,
    const float* __restrict__ be1, float* __restrict__ h,
    float* __restrict__ ti, float* __restrict__ aj)
{
    __shared__ float sx[RT][DD];
    int d = threadIdx.x;
    int row0 = blockIdx.x * RT;
    for (int r = 0; r < RT; ++r) sx[r][d] = node[(row0 + r) * DD + d];
    __syncthreads();
    float bnd = bn[d], be1d = be1[d];
    float acc_h[RT], acc_i[RT], acc_j[RT];
    for (int r = 0; r < RT; ++r) { acc_h[r] = bnd; acc_i[r] = be1d; acc_j[r] = 0.f; }
    for (int k = 0; k < DD; ++k) {
        float w0 = Wn[k * DD + d];
        float w1 = We1[k * DD + d];
        float w2 = We1[(DD + k) * DD + d];
        for (int r = 0; r < RT; ++r) {
            float x = sx[r][k];
            acc_h[r] = fmaf(x, w0, acc_h[r]);
            acc_i[r] = fmaf(x, w1, acc_i[r]);
            acc_j[r] = fmaf(x, w2, acc_j[r]);
        }
    }
    for (int r = 0; r < RT; ++r) {
        h [(row0 + r) * DD + d] = acc_h[r];
        ti[(row0 + r) * DD + d] = acc_i[r];
        aj[(row0 + r) * DD + d] = acc_j[r];
    }
}

// ---------------- Kernel B: edge scores + masked softmax -> w (B,N,N)
#define IT 4
#define CH 32
__global__ __launch_bounds__(256) void edge_kernel(
    const float* __restrict__ ti, const float* __restrict__ aj,
    const float* __restrict__ rel, const int* __restrict__ adj,
    const float* __restrict__ We1, const float* __restrict__ We2,
    const float* __restrict__ be2, float* __restrict__ wout)
{
    __shared__ float s_ajc[NN * (CH + 1)];
    __shared__ float s_red[IT][4];
    int tid = threadIdx.x;
    int b  = blockIdx.x / (NN / IT);
    int i0 = (blockIdx.x % (NN / IT)) * IT;
    int j = tid;

    const float2* rel2 = (const float2*)rel;
    float rx[IT], ry[IT], dist[IT];
    int msk[IT];
    for (int r = 0; r < IT; ++r) {
        float2 rp = rel2[(b * NN + i0 + r) * NN + j];
        rx[r] = rp.x; ry[r] = rp.y;
        dist[r] = sqrtf(rp.x * rp.x + rp.y * rp.y);
        msk[r] = adj[(b * NN + i0 + r) * NN + j];
    }
    float be2v = be2[0];
    float score[IT];
    for (int r = 0; r < IT; ++r) score[r] = be2v;

    for (int dc = 0; dc < DD / CH; ++dc) {
        __syncthreads();
        for (int idx = tid; idx < NN * CH; idx += 256) {
            int rrow = idx >> 5, col = idx & (CH - 1);
            s_ajc[rrow * (CH + 1) + col] = aj[(b * NN + rrow) * DD + dc * CH + col];
        }
        __syncthreads();
        for (int d = 0; d < CH; ++d) {
            int dd = dc * CH + d;
            float a  = s_ajc[j * (CH + 1) + d];
            // uniform scalar loads (s_load): rel weights + We2 + ti rows
            float w0 = We1[(2 * DD + 0) * DD + dd];
            float w1 = We1[(2 * DD + 1) * DD + dd];
            float w2 = We1[(2 * DD + 2) * DD + dd];
            float e2 = We2[dd];
            for (int r = 0; r < IT; ++r) {
                float t = ti[(b * NN + i0 + r) * DD + dd];
                float v = t + a + rx[r] * w0 + ry[r] * w1 + dist[r] * w2;
                v = fmaxf(v, 0.f);
                score[r] = fmaf(v, e2, score[r]);
            }
        }
    }
    for (int r = 0; r < IT; ++r) if (msk[r] == 0) score[r] = -3.0e38f;

    int wave = tid >> 6, lane = tid & 63;
    float M[IT], S[IT], e[IT];
    for (int r = 0; r < IT; ++r) {
        float m = score[r];
        for (int off = 32; off > 0; off >>= 1) m = fmaxf(m, __shfl_xor(m, off));
        if (lane == 0) s_red[r][wave] = m;
    }
    __syncthreads();
    for (int r = 0; r < IT; ++r)
        M[r] = fmaxf(fmaxf(s_red[r][0], s_red[r][1]), fmaxf(s_red[r][2], s_red[r][3]));
    for (int r = 0; r < IT; ++r) e[r] = (msk[r] == 0) ? 0.f : __expf(score[r] - M[r]);
    __syncthreads();
    for (int r = 0; r < IT; ++r) {
        float s = e[r];
        for (int off = 32; off > 0; off >>= 1) s += __shfl_xor(s, off);
        if (lane == 0) s_red[r][wave] = s;
    }
    __syncthreads();
    for (int r = 0; r < IT; ++r) {
        S[r] = s_red[r][0] + s_red[r][1] + s_red[r][2] + s_red[r][3];
        wout[(b * NN + i0 + r) * NN + j] = e[r] / S[r];
    }
}

// ---------------- Kernel C1: messages = w @ h
#define RT2 8
__global__ __launch_bounds__(128) void msg_kernel(
    const float* __restrict__ w, const float* __restrict__ h,
    float* __restrict__ msg)
{
    __shared__ float s_w[RT2][NN];
    int d = threadIdx.x;
    int b  = blockIdx.x / (NN / RT2);
    int i0 = (blockIdx.x % (NN / RT2)) * RT2;
    for (int idx = d; idx < RT2 * NN; idx += 128) {
        int r = idx >> 8, j = idx & (NN - 1);
        s_w[r][j] = w[(b * NN + i0 + r) * NN + j];
    }
    __syncthreads();
    float acc[RT2] = {};
    for (int j = 0; j < NN; ++j) {
        float hv = h[(b * NN + j) * DD + d];
        for (int r = 0; r < RT2; ++r) acc[r] = fmaf(s_w[r][j], hv, acc[r]);
    }
    for (int r = 0; r < RT2; ++r) msg[(b * NN + i0 + r) * DD + d] = acc[r];
}

// ---------------- Kernel C2: agg = relu(msg@Wa+ba); x = node+agg; LayerNorm
#define RT3 4
__global__ __launch_bounds__(128) void out_kernel(
    const float* __restrict__ msg, const float* __restrict__ Wa,
    const float* __restrict__ ba, const float* __restrict__ node,
    const float* __restrict__ gamma, const float* __restrict__ beta,
    float* __restrict__ out)
{
    __shared__ float s_m[RT3][DD];
    __shared__ float s_red[RT3][2][2];
    int d = threadIdx.x;
    int b  = blockIdx.x / (NN / RT3);
    int i0 = (blockIdx.x % (NN / RT3)) * RT3;
    for (int r = 0; r < RT3; ++r) s_m[r][d] = msg[(b * NN + i0 + r) * DD + d];
    __syncthreads();
    float bad = ba[d];
    float acc[RT3];
    for (int r = 0; r < RT3; ++r) acc[r] = bad;
    for (int k = 0; k < DD; ++k) {
        float wv = Wa[k * DD + d];
        for (int r = 0; r < RT3; ++r) acc[r] = fmaf(s_m[r][k], wv, acc[r]);
    }
    int wave = d >> 6, lane = d & 63;
    float g = gamma[d], bt = beta[d];
    float xv[RT3];
    for (int r = 0; r < RT3; ++r) {
        float x = node[(b * NN + i0 + r) * DD + d] + fmaxf(acc[r], 0.f);
        xv[r] = x;
        float s1 = x, s2 = x * x;
        for (int off = 32; off > 0; off >>= 1) {
            s1 += __shfl_xor(s1, off);
            s2 += __shfl_xor(s2, off);
        }
        if (lane == 0) { s_red[r][wave][0] = s1; s_red[r][wave][1] = s2; }
    }
    __syncthreads();
    for (int r = 0; r < RT3; ++r) {
        float s1 = s_red[r][0][0] + s_red[r][1][0];
        float s2 = s_red[r][0][1] + s_red[r][1][1];
        float mu  = s1 * (1.0f / DD);
        float var = s2 * (1.0f / DD) - mu * mu;
        float inv = rsqrtf(var + 1e-5f);
        out[(b * NN + i0 + r) * DD + d] = (xv[r] - mu) * inv * g + bt;
    }
}

extern "C" void kernel_launch(void* const* d_in, const int* in_sizes, int n_in,
                              void* d_out, int out_size, void* d_ws, size_t ws_size,
                              hipStream_t stream) {
    const float* node = (const float*)d_in[0];
    const int*   adj  = (const int*)d_in[1];
    const float* rel  = (const float*)d_in[2];
    const float* Wn   = (const float*)d_in[3];
    const float* bn   = (const float*)d_in[4];
    const float* We1  = (const float*)d_in[5];
    const float* be1  = (const float*)d_in[6];
    const float* We2  = (const float*)d_in[7];
    const float* be2  = (const float*)d_in[8];
    const float* Wa   = (const float*)d_in[9];
    const float* ba   = (const float*)d_in[10];
    const float* gamma = (const float*)d_in[11];
    const float* beta  = (const float*)d_in[12];
    float* out = (float*)d_out;

    float* ws  = (float*)d_ws;
    const int ROWS = BB * NN * DD;          // 262144
    float* h   = ws;
    float* ti  = ws + ROWS;
    float* aj  = ws + 2 * ROWS;
    float* wsm = ws + 3 * ROWS;             // B*N*N = 524288
    float* msg = ws + 3 * ROWS + BB * NN * NN;

    prep_kernel<<<BB * NN / RT, 128, 0, stream>>>(node, Wn, bn, We1, be1, h, ti, aj);
    edge_kernel<<<BB * NN / IT, 256, 0, stream>>>(ti, aj, rel, adj, We1, We2, be2, wsm);
    msg_kernel<<<BB * NN / RT2, 128, 0, stream>>>(wsm, h, msg);
    out_kernel<<<BB * NN / RT3, 128, 0, stream>>>(msg, Wa, ba, node, gamma, beta, out);
}

// Round 2
// 137.340 us; speedup vs baseline: 1.1128x; 1.1128x over previous
//
#include <hip/hip_runtime.h>
#include <math.h>

#define BB 8
#define NN 256
#define DD 128

// ---------------- Kernel A: h = node@Wn+bn, ti = node@We1[:D]+be1, aj = node@We1[D:2D]
#define RT 4
__global__ __launch_bounds__(128) void prep_kernel(
    const float* __restrict__ node, const float* __restrict__ Wn,
    const float* __restrict__ bn, const float* __restrict__ We1,
    const float* __restrict__ be1, float* __restrict__ h,
    float* __restrict__ ti, float* __restrict__ aj)
{
    __shared__ float sx[RT][DD];
    int d = threadIdx.x;
    int row0 = blockIdx.x * RT;
    // float4 staging: RT*DD/4 = 128 float4s, one per thread
    {
        int r = d >> 5;
        int c = (d & 31) << 2;
        *(float4*)&sx[r][c] = *(const float4*)&node[(row0 + r) * DD + c];
    }
    __syncthreads();
    float bnd = bn[d], be1d = be1[d];
    float acc_h[RT], acc_i[RT], acc_j[RT];
    #pragma unroll
    for (int r = 0; r < RT; ++r) { acc_h[r] = bnd; acc_i[r] = be1d; acc_j[r] = 0.f; }
    for (int k = 0; k < DD; k += 4) {
        float x0[RT], x1[RT], x2[RT], x3[RT];
        #pragma unroll
        for (int r = 0; r < RT; ++r) {
            float4 v = *(const float4*)&sx[r][k];
            x0[r] = v.x; x1[r] = v.y; x2[r] = v.z; x3[r] = v.w;
        }
        #pragma unroll
        for (int kk = 0; kk < 4; ++kk) {
            float w0 = Wn[(k + kk) * DD + d];
            float w1 = We1[(k + kk) * DD + d];
            float w2 = We1[(DD + k + kk) * DD + d];
            #pragma unroll
            for (int r = 0; r < RT; ++r) {
                float x = (kk == 0) ? x0[r] : (kk == 1) ? x1[r] : (kk == 2) ? x2[r] : x3[r];
                acc_h[r] = fmaf(x, w0, acc_h[r]);
                acc_i[r] = fmaf(x, w1, acc_i[r]);
                acc_j[r] = fmaf(x, w2, acc_j[r]);
            }
        }
    }
    #pragma unroll
    for (int r = 0; r < RT; ++r) {
        h [(row0 + r) * DD + d] = acc_h[r];
        ti[(row0 + r) * DD + d] = acc_i[r];
        aj[(row0 + r) * DD + d] = acc_j[r];
    }
}

// ---------------- Kernel B: edge scores + masked softmax -> w (B,N,N)
#define IT 4
#define CH 32
#define STR (CH + 1)
__global__ __launch_bounds__(256) void edge_kernel(
    const float* __restrict__ ti, const float* __restrict__ aj,
    const float* __restrict__ rel, const int* __restrict__ adj,
    const float* __restrict__ We1, const float* __restrict__ We2,
    const float* __restrict__ be2, float* __restrict__ wout)
{
    __shared__ float s_ajc[NN * STR];
    __shared__ float s_red[IT][4];
    int tid = threadIdx.x;
    int b  = blockIdx.x / (NN / IT);
    int i0 = (blockIdx.x % (NN / IT)) * IT;
    int j = tid;

    const float2* rel2 = (const float2*)rel;
    float rx[IT], ry[IT], dist[IT];
    int msk[IT];
    #pragma unroll
    for (int r = 0; r < IT; ++r) {
        float2 rp = rel2[(b * NN + i0 + r) * NN + j];
        rx[r] = rp.x; ry[r] = rp.y;
        dist[r] = sqrtf(rp.x * rp.x + rp.y * rp.y);
        msk[r] = adj[(b * NN + i0 + r) * NN + j];
    }
    float be2v = be2[0];
    float score[IT];
    #pragma unroll
    for (int r = 0; r < IT; ++r) score[r] = be2v;

    const float* ti_b = ti + ((long)b * NN + i0) * DD;
    const float* w0p = We1 + (2 * DD + 0) * DD;
    const float* w1p = We1 + (2 * DD + 1) * DD;
    const float* w2p = We1 + (2 * DD + 2) * DD;

    for (int dc = 0; dc < DD; dc += CH) {
        __syncthreads();
        // stage aj chunk with float4 global loads
        #pragma unroll
        for (int it = 0; it < 8; ++it) {
            int idx = tid + it * 256;            // 0..2047 float4s
            int rrow = idx >> 3;
            int c4 = (idx & 7) << 2;
            float4 v = *(const float4*)(aj + (b * NN + rrow) * DD + dc + c4);
            float* p = &s_ajc[rrow * STR + c4];
            p[0] = v.x; p[1] = v.y; p[2] = v.z; p[3] = v.w;
        }
        __syncthreads();
        #pragma unroll 4
        for (int d = 0; d < CH; d += 2) {
            int dd = dc + d;
            float a0 = s_ajc[j * STR + d];
            float a1 = s_ajc[j * STR + d + 1];
            float2 w0 = *(const float2*)(w0p + dd);
            float2 w1 = *(const float2*)(w1p + dd);
            float2 w2 = *(const float2*)(w2p + dd);
            float2 e2 = *(const float2*)(We2 + dd);
            #pragma unroll
            for (int r = 0; r < IT; ++r) {
                float2 t = *(const float2*)(ti_b + r * DD + dd);
                float v0 = fmaf(rx[r], w0.x, t.x + a0);
                v0 = fmaf(ry[r], w1.x, v0);
                v0 = fmaf(dist[r], w2.x, v0);
                v0 = fmaxf(v0, 0.f);
                float v1 = fmaf(rx[r], w0.y, t.y + a1);
                v1 = fmaf(ry[r], w1.y, v1);
                v1 = fmaf(dist[r], w2.y, v1);
                v1 = fmaxf(v1, 0.f);
                score[r] = fmaf(v0, e2.x, score[r]);
                score[r] = fmaf(v1, e2.y, score[r]);
            }
        }
    }
    #pragma unroll
    for (int r = 0; r < IT; ++r) if (msk[r] == 0) score[r] = -3.0e38f;

    int wave = tid >> 6, lane = tid & 63;
    float M[IT], S[IT], e[IT];
    #pragma unroll
    for (int r = 0; r < IT; ++r) {
        float m = score[r];
        for (int off = 32; off > 0; off >>= 1) m = fmaxf(m, __shfl_xor(m, off));
        if (lane == 0) s_red[r][wave] = m;
    }
    __syncthreads();
    #pragma unroll
    for (int r = 0; r < IT; ++r)
        M[r] = fmaxf(fmaxf(s_red[r][0], s_red[r][1]), fmaxf(s_red[r][2], s_red[r][3]));
    #pragma unroll
    for (int r = 0; r < IT; ++r) e[r] = (msk[r] == 0) ? 0.f : __expf(score[r] - M[r]);
    __syncthreads();
    #pragma unroll
    for (int r = 0; r < IT; ++r) {
        float s = e[r];
        for (int off = 32; off > 0; off >>= 1) s += __shfl_xor(s, off);
        if (lane == 0) s_red[r][wave] = s;
    }
    __syncthreads();
    #pragma unroll
    for (int r = 0; r < IT; ++r) {
        S[r] = s_red[r][0] + s_red[r][1] + s_red[r][2] + s_red[r][3];
        wout[(b * NN + i0 + r) * NN + j] = e[r] / S[r];
    }
}

// ---------------- Kernel C: msg = w@h; agg = relu(msg@Wa+ba); x = node+agg; LayerNorm
#define RT2 4
__global__ __launch_bounds__(128) void msgout_kernel(
    const float* __restrict__ w, const float* __restrict__ h,
    const float* __restrict__ Wa, const float* __restrict__ ba,
    const float* __restrict__ node, const float* __restrict__ gamma,
    const float* __restrict__ beta, float* __restrict__ out)
{
    __shared__ float s_w[RT2][NN];
    __shared__ float s_m[RT2][DD];
    __shared__ float s_red[RT2][2][2];
    int d = threadIdx.x;
    int b  = blockIdx.x / (NN / RT2);
    int i0 = (blockIdx.x % (NN / RT2)) * RT2;
    // stage w rows: RT2*NN/4 = 256 float4s, 2 per thread
    #pragma unroll
    for (int it = 0; it < 2; ++it) {
        int idx = d + it * 128;                 // 0..255
        int r = idx >> 6;
        int c = (idx & 63) << 2;
        *(float4*)&s_w[r][c] = *(const float4*)&w[(b * NN + i0 + r) * NN + c];
    }
    __syncthreads();
    float acc[RT2] = {0.f, 0.f, 0.f, 0.f};
    for (int jj = 0; jj < NN; jj += 4) {
        float4 wv[RT2];
        #pragma unroll
        for (int r = 0; r < RT2; ++r) wv[r] = *(const float4*)&s_w[r][jj];
        #pragma unroll
        for (int q = 0; q < 4; ++q) {
            float hv = h[(b * NN + jj + q) * DD + d];
            #pragma unroll
            for (int r = 0; r < RT2; ++r) {
                float wq = (q == 0) ? wv[r].x : (q == 1) ? wv[r].y : (q == 2) ? wv[r].z : wv[r].w;
                acc[r] = fmaf(wq, hv, acc[r]);
            }
        }
    }
    #pragma unroll
    for (int r = 0; r < RT2; ++r) s_m[r][d] = acc[r];
    __syncthreads();
    float bad = ba[d];
    float agg[RT2];
    #pragma unroll
    for (int r = 0; r < RT2; ++r) agg[r] = bad;
    for (int k = 0; k < DD; k += 4) {
        float4 mv[RT2];
        #pragma unroll
        for (int r = 0; r < RT2; ++r) mv[r] = *(const float4*)&s_m[r][k];
        #pragma unroll
        for (int q = 0; q < 4; ++q) {
            float wv = Wa[(k + q) * DD + d];
            #pragma unroll
            for (int r = 0; r < RT2; ++r) {
                float mq = (q == 0) ? mv[r].x : (q == 1) ? mv[r].y : (q == 2) ? mv[r].z : mv[r].w;
                agg[r] = fmaf(mq, wv, agg[r]);
            }
        }
    }
    int wave = d >> 6, lane = d & 63;
    float g = gamma[d], bt = beta[d];
    float xv[RT2];
    #pragma unroll
    for (int r = 0; r < RT2; ++r) {
        float x = node[(b * NN + i0 + r) * DD + d] + fmaxf(agg[r], 0.f);
        xv[r] = x;
        float s1 = x, s2 = x * x;
        for (int off = 32; off > 0; off >>= 1) {
            s1 += __shfl_xor(s1, off);
            s2 += __shfl_xor(s2, off);
        }
        if (lane == 0) { s_red[r][wave][0] = s1; s_red[r][wave][1] = s2; }
    }
    __syncthreads();
    #pragma unroll
    for (int r = 0; r < RT2; ++r) {
        float s1 = s_red[r][0][0] + s_red[r][1][0];
        float s2 = s_red[r][0][1] + s_red[r][1][1];
        float mu  = s1 * (1.0f / DD);
        float var = s2 * (1.0f / DD) - mu * mu;
        float inv = rsqrtf(var + 1e-5f);
        out[(b * NN + i0 + r) * DD + d] = (xv[r] - mu) * inv * g + bt;
    }
}

extern "C" void kernel_launch(void* const* d_in, const int* in_sizes, int n_in,
                              void* d_out, int out_size, void* d_ws, size_t ws_size,
                              hipStream_t stream) {
    const float* node = (const float*)d_in[0];
    const int*   adj  = (const int*)d_in[1];
    const float* rel  = (const float*)d_in[2];
    const float* Wn   = (const float*)d_in[3];
    const float* bn   = (const float*)d_in[4];
    const float* We1  = (const float*)d_in[5];
    const float* be1  = (const float*)d_in[6];
    const float* We2  = (const float*)d_in[7];
    const float* be2  = (const float*)d_in[8];
    const float* Wa   = (const float*)d_in[9];
    const float* ba   = (const float*)d_in[10];
    const float* gamma = (const float*)d_in[11];
    const float* beta  = (const float*)d_in[12];
    float* out = (float*)d_out;

    float* ws  = (float*)d_ws;
    const int ROWS = BB * NN * DD;          // 262144
    float* h   = ws;
    float* ti  = ws + ROWS;
    float* aj  = ws + 2 * ROWS;
    float* wsm = ws + 3 * ROWS;             // B*N*N = 524288

    prep_kernel<<<BB * NN / RT, 128, 0, stream>>>(node, Wn, bn, We1, be1, h, ti, aj);
    edge_kernel<<<BB * NN / IT, 256, 0, stream>>>(ti, aj, rel, adj, We1, We2, be2, wsm);
    msgout_kernel<<<BB * NN / RT2, 128, 0, stream>>>(wsm, h, Wa, ba, node, gamma, beta, out);
}